// Round 1
// baseline (814.466 us; speedup 1.0000x reference)
//
#include <hip/hip_runtime.h>
#include <hip/hip_bf16.h>
#include <hip/hip_fp16.h>
#include <stdint.h>

typedef __attribute__((ext_vector_type(8))) short short8;
typedef __attribute__((ext_vector_type(4))) float float4v;

#define NEG_SLOPE 0.01f
#define LDS_S 136  // h-tile row stride (elems): mult of 8 for 16B-aligned ds_read_b128

// fixed-point pack params for edge_attr accumulation:
// u = round((v + BIAS) * SCALE), 4 x 16-bit fields per u64.
// field sum = SCALE*sum(v) + BIAS*SCALE*cnt; capacity 65536 -> deg < 65536/((BIAS+6)*SCALE) ~ 146
#define FXP_BIAS 8.0f
#define FXP_SCALE 32.0f
#define FXP_INV_SCALE 0.03125f

__device__ __forceinline__ float bf2f(uint16_t u) {
    union { uint32_t i; float f; } c; c.i = ((uint32_t)u) << 16; return c.f;
}
__device__ __forceinline__ uint16_t f2bf(float f) {
    union { float ff; uint32_t i; } c; c.ff = f;
    uint32_t x = c.i;
    x += 0x7fffu + ((x >> 16) & 1u);   // RNE
    return (uint16_t)(x >> 16);
}

// ---------- pack W1/W2 (fp32) into bf16 MFMA B-fragment order ----------
// B-frag (16x16x32): lane holds B[k=(lane>>4)*8+j][n=lane&15], j=0..7
__global__ __launch_bounds__(256) void pack_w(
    const float* __restrict__ W1, const float* __restrict__ W2,
    uint16_t* __restrict__ W1p, uint16_t* __restrict__ W2p)
{
    int pid = blockIdx.x * 256 + threadIdx.x;
    if (pid < 20480) {                       // W1: 8 ct * 5 kc * 64 * 8
        int j = pid & 7, lane = (pid >> 3) & 63, rest = pid >> 9;
        int kc = rest % 5, ct = rest / 5;
        int k = kc * 32 + (lane >> 4) * 8 + j;
        int n = ct * 16 + (lane & 15);
        W1p[pid] = f2bf(W1[k * 128 + n]);
    }
    int pid2 = pid - 20480;
    if (pid2 >= 0 && pid2 < 16384) {         // W2: 8 ct * 4 kc * 64 * 8
        int j = pid2 & 7, lane = (pid2 >> 3) & 63, rest = pid2 >> 9;
        int kc = rest & 3, ct = rest >> 2;
        int k = kc * 32 + (lane >> 4) * 8 + j;
        int n = ct * 16 + (lane & 15);
        W2p[pid2] = f2bf(W2[k * 128 + n]);
    }
}

// ---------- scatter: edge_attr (fp32) -> per-node packed fixed-point sums + u32 counts ----
// 4 threads per edge, each owns 4 dims packed into one u64 (4 x 16-bit fields).
// One global_atomic_add_x2 per array (vs 2 x pk_add_f16 before): halves atomic op count.
__global__ __launch_bounds__(256) void scatter_kernel(
    const float* __restrict__ ea, const int* __restrict__ eidx, int E,
    unsigned long long* __restrict__ rec_pack, unsigned long long* __restrict__ sent_pack,
    uint32_t* __restrict__ rec_cnt, uint32_t* __restrict__ sent_cnt)
{
    int gid = blockIdx.x * 256 + threadIdx.x;
    int e = gid >> 2;
    if (e >= E) return;
    int t = gid & 3;
    float4 v = *(const float4*)(ea + (size_t)e * 16 + t * 4);
    uint32_t u0 = __float2uint_rn((v.x + FXP_BIAS) * FXP_SCALE);
    uint32_t u1 = __float2uint_rn((v.y + FXP_BIAS) * FXP_SCALE);
    uint32_t u2 = __float2uint_rn((v.z + FXP_BIAS) * FXP_SCALE);
    uint32_t u3 = __float2uint_rn((v.w + FXP_BIAS) * FXP_SCALE);
    unsigned long long p = (unsigned long long)u0
                         | ((unsigned long long)u1 << 16)
                         | ((unsigned long long)u2 << 32)
                         | ((unsigned long long)u3 << 48);
    int row = eidx[e];
    int col = eidx[E + e];
    atomicAdd(rec_pack  + (size_t)row * 4 + t, p);
    atomicAdd(sent_pack + (size_t)col * 4 + t, p);
    if (t == 0) {
        atomicAdd(rec_cnt + row, 1u);
        atomicAdd(sent_cnt + col, 1u);
    }
}

// ---------- fused MLP: [x|rec_mean|sent_mean] @ W1 -> leaky -> @ W2 ----------
// block = 256 = 4 waves; wave handles 16 nodes x 128 cols via 16x16x32 bf16 MFMA
__global__ __launch_bounds__(256) void mlp_kernel(
    const float* __restrict__ x,          // [N,128] fp32
    const unsigned long long* __restrict__ rec_pack,
    const unsigned long long* __restrict__ sent_pack,
    const uint32_t* __restrict__ rec_cnt, const uint32_t* __restrict__ sent_cnt,
    const uint16_t* __restrict__ W1p, const uint16_t* __restrict__ W2p,
    const float* __restrict__ b1, const float* __restrict__ b2,
    float* __restrict__ out, int N)
{
    __shared__ alignas(16) uint16_t hbuf[4 * 16 * LDS_S];
    int wave = threadIdx.x >> 6;
    int lane = threadIdx.x & 63;
    int m = lane & 15, q = lane >> 4;
    int nw = blockIdx.x * 64 + wave * 16;
    int node = nw + m;
    int nclamp = node < N ? node : N - 1;

    // A fragments: A[m=lane&15][k=q*8+j]; d_in = 160 = 5 K-chunks of 32
    short8 afr[5];
    {
        const float* xf = x + (size_t)nclamp * 128;
        #pragma unroll
        for (int kc = 0; kc < 4; ++kc) {
            float4 v0 = *(const float4*)(xf + kc * 32 + q * 8);
            float4 v1 = *(const float4*)(xf + kc * 32 + q * 8 + 4);
            short8 a;
            a[0] = (short)f2bf(v0.x); a[1] = (short)f2bf(v0.y);
            a[2] = (short)f2bf(v0.z); a[3] = (short)f2bf(v0.w);
            a[4] = (short)f2bf(v1.x); a[5] = (short)f2bf(v1.y);
            a[6] = (short)f2bf(v1.z); a[7] = (short)f2bf(v1.w);
            afr[kc] = a;
        }
    }
    {   // chunk 4: k=128..159 -> [rec_mean(16) | sent_mean(16)]
        // q<2: rec dims q*8..q*8+7  -> rec_pack[node*4 + q*2 .. +1]
        // q>=2: sent dims (q-2)*8.. -> sent_pack[node*4 + (q-2)*2 .. +1]
        const unsigned long long* psrc = (q < 2)
            ? (rec_pack  + (size_t)nclamp * 4 + q * 2)
            : (sent_pack + (size_t)nclamp * 4 + (q - 2) * 2);
        uint32_t cu = (q < 2) ? rec_cnt[nclamp] : sent_cnt[nclamp];
        float cntf = (float)cu;
        float inv = cu ? 1.0f / cntf : 0.0f;   // cnt==0 -> sum==0 -> mean 0 (matches ref max(cnt,1))
        float biasterm = FXP_BIAS * FXP_SCALE * cntf;   // 256 * cnt
        short8 a;
        #pragma unroll
        for (int jj = 0; jj < 2; ++jj) {
            unsigned long long pv = psrc[jj];
            #pragma unroll
            for (int f = 0; f < 4; ++f) {
                float fld = (float)((uint32_t)(pv >> (16 * f)) & 0xFFFFu);
                float sum = (fld - biasterm) * FXP_INV_SCALE;
                a[jj * 4 + f] = (short)f2bf(sum * inv);
            }
        }
        afr[4] = a;
    }

    uint16_t* hw = hbuf + wave * 16 * LDS_S;

    // GEMM1 + bias + LeakyReLU -> LDS (bf16)
    #pragma unroll
    for (int ct = 0; ct < 8; ++ct) {
        float4v acc = {0.f, 0.f, 0.f, 0.f};
        #pragma unroll
        for (int kc = 0; kc < 5; ++kc) {
            short8 bfr = *(const short8*)(W1p + ((ct * 5 + kc) * 64 + lane) * 8);
            acc = __builtin_amdgcn_mfma_f32_16x16x32_bf16(afr[kc], bfr, acc, 0, 0, 0);
        }
        int c = ct * 16 + m;                 // C/D: col = lane&15, row = q*4+r
        float bias = b1[c];
        #pragma unroll
        for (int r = 0; r < 4; ++r) {
            float h = acc[r] + bias;
            h = h >= 0.f ? h : NEG_SLOPE * h;
            hw[(q * 4 + r) * LDS_S + c] = f2bf(h);
        }
    }
    __syncthreads();

    // A2 fragments of h from LDS
    short8 a2[4];
    #pragma unroll
    for (int kc = 0; kc < 4; ++kc)
        a2[kc] = *(const short8*)(hw + m * LDS_S + kc * 32 + q * 8);

    // GEMM2 + bias -> out (fp32)
    #pragma unroll
    for (int ct = 0; ct < 8; ++ct) {
        float4v acc = {0.f, 0.f, 0.f, 0.f};
        #pragma unroll
        for (int kc = 0; kc < 4; ++kc) {
            short8 bfr = *(const short8*)(W2p + ((ct * 4 + kc) * 64 + lane) * 8);
            acc = __builtin_amdgcn_mfma_f32_16x16x32_bf16(a2[kc], bfr, acc, 0, 0, 0);
        }
        int c = ct * 16 + m;
        float bias = b2[c];
        #pragma unroll
        for (int r = 0; r < 4; ++r) {
            int onode = nw + q * 4 + r;
            if (onode < N)
                out[(size_t)onode * 128 + c] = acc[r] + bias;
        }
    }
}

extern "C" void kernel_launch(void* const* d_in, const int* in_sizes, int n_in,
                              void* d_out, int out_size, void* d_ws, size_t ws_size,
                              hipStream_t stream) {
    const float* x   = (const float*)d_in[0];
    const int* eidx  = (const int*)d_in[1];
    const float* ea  = (const float*)d_in[2];
    const float* W1  = (const float*)d_in[3];
    const float* b1  = (const float*)d_in[4];
    const float* W2  = (const float*)d_in[5];
    const float* b2  = (const float*)d_in[6];
    float* out = (float*)d_out;
    int N = in_sizes[0] / 128;
    int E = in_sizes[1] / 2;

    unsigned long long* rec_pack  = (unsigned long long*)d_ws;         // N*4 u64
    unsigned long long* sent_pack = rec_pack + (size_t)N * 4;          // N*4 u64
    uint32_t* rec_cnt  = (uint32_t*)(sent_pack + (size_t)N * 4);       // N u32
    uint32_t* sent_cnt = rec_cnt + N;                                  // N u32
    uint16_t* W1p      = (uint16_t*)(sent_cnt + N);                    // 20480 bf16
    uint16_t* W2p      = W1p + 20480;                                  // 16384 bf16

    // zero packed sums + counts; ws is poisoned 0xAA before each call
    size_t zero_bytes = (size_t)N * 8 * sizeof(unsigned long long)
                      + (size_t)2 * N * sizeof(uint32_t);
    hipMemsetAsync(d_ws, 0, zero_bytes, stream);

    pack_w<<<(20480 + 16384 + 255) / 256, 256, 0, stream>>>(W1, W2, W1p, W2p);

    int sblocks = (E * 4 + 255) / 256;
    scatter_kernel<<<sblocks, 256, 0, stream>>>(ea, eidx, E,
                                                rec_pack, sent_pack, rec_cnt, sent_cnt);

    mlp_kernel<<<(N + 63) / 64, 256, 0, stream>>>(x, rec_pack, sent_pack, rec_cnt, sent_cnt,
                                                  W1p, W2p, b1, b2, out, N);
}